// Round 1
// baseline (726.447 us; speedup 1.0000x reference)
//
#include <hip/hip_runtime.h>
#include <hip/hip_bf16.h>

// Problem constants
#define BATCH 2
#define CH 256
#define NH 8
#define HD 32
#define NPOS 2304            // 48*48
#define SCALE 0.17677669529663687f   // 32^-0.5

// ---------------------------------------------------------------------------
// Tiled fp32 GEMM: Y[o][n] = sum_c W[o][c] * X[c][n] + bias[o]
// X: [B][C][N] (n contiguous). W: [C][C] row-major ([o][c]).
// out_layout 0: Y index = ((b*C + o)*N + n)          (channel layout)
// out_layout 1: Y index = ((b*NH + o/32)*N + n)*32 + o%32  (heads layout)
// Tile: 64 o x 64 n, K-chunk 16, 256 threads, 4x4 micro-tile per thread.
// ---------------------------------------------------------------------------
__global__ __launch_bounds__(256) void proj_gemm(
    const float* __restrict__ X,
    const float* __restrict__ W,
    const float* __restrict__ bias,
    float* __restrict__ Y,
    int out_layout)
{
    const int N = NPOS, C = CH;
    int b  = blockIdx.z;
    int n0 = blockIdx.x * 64;
    int o0 = blockIdx.y * 64;
    const float* Xb = X + (size_t)b * C * N;

    __shared__ float Xs[16][64];
    __shared__ float Ws[16][65];

    int t  = threadIdx.x;
    int oo = (t & 15) * 4;
    int nn = (t >> 4) * 4;

    float acc[4][4] = {};

    for (int c0 = 0; c0 < C; c0 += 16) {
        // X tile: 16 c-rows x 64 n
        {
            int kc = t >> 6;      // 0..3
            int nl = t & 63;
            #pragma unroll
            for (int i = 0; i < 4; ++i)
                Xs[kc + i * 4][nl] = Xb[(size_t)(c0 + kc + i * 4) * N + n0 + nl];
        }
        // W tile transposed into LDS: Ws[kc][o]
        {
            int ol = t >> 4;      // 0..15
            int kc = t & 15;
            #pragma unroll
            for (int i = 0; i < 4; ++i)
                Ws[kc][ol + i * 16] = W[(size_t)(o0 + ol + i * 16) * C + c0 + kc];
        }
        __syncthreads();
        #pragma unroll
        for (int kc = 0; kc < 16; ++kc) {
            float xr[4], wr[4];
            #pragma unroll
            for (int i = 0; i < 4; ++i) xr[i] = Xs[kc][nn + i];
            #pragma unroll
            for (int i = 0; i < 4; ++i) wr[i] = Ws[kc][oo + i];
            #pragma unroll
            for (int i = 0; i < 4; ++i)
                #pragma unroll
                for (int j = 0; j < 4; ++j)
                    acc[i][j] += wr[i] * xr[j];
        }
        __syncthreads();
    }

    #pragma unroll
    for (int i = 0; i < 4; ++i) {
        int o = o0 + oo + i;
        float bv = bias[o];
        #pragma unroll
        for (int j = 0; j < 4; ++j) {
            int n = n0 + nn + j;
            float v = acc[i][j] + bv;
            size_t idx;
            if (out_layout == 0)
                idx = ((size_t)b * C + o) * N + n;
            else
                idx = (((size_t)b * NH + (o >> 5)) * N + n) * (size_t)HD + (o & 31);
            Y[idx] = v;
        }
    }
}

// ---------------------------------------------------------------------------
// Flash attention, fp32. Q/K/V: [B*NH][N][32]. O: [B][C][N] with c = h*32+d.
// Block: 256 threads = 64 Q-rows x 4 lanes. Each thread: full Q row in regs,
// computes 16 keys' scores per 64-key tile, owns 8 output dims.
// ---------------------------------------------------------------------------
__global__ __launch_bounds__(256) void attn_kernel(
    const float* __restrict__ Q,
    const float* __restrict__ K,
    const float* __restrict__ V,
    float* __restrict__ O)
{
    const int N = NPOS, D = HD;
    int bh = blockIdx.y;            // 0..15
    int b = bh >> 3, h = bh & 7;
    int n0 = blockIdx.x * 64;

    const float* Qb = Q + (size_t)bh * N * D;
    const float* Kb = K + (size_t)bh * N * D;
    const float* Vb = V + (size_t)bh * N * D;

    __shared__ float Ks[64][32];
    __shared__ float Vs[64][32];
    __shared__ float Ps[64][68];    // row stride 272B (16B aligned), padded

    int t  = threadIdx.x;
    int r  = t >> 2;                // 0..63: Q row within tile
    int c4 = t & 3;                 // quarter

    // Q row -> registers (4 lanes redundant per row; L2-served)
    float qreg[32];
    #pragma unroll
    for (int i = 0; i < 8; ++i) {
        float4 v4 = *(const float4*)&Qb[(size_t)(n0 + r) * D + i * 4];
        qreg[i*4+0] = v4.x; qreg[i*4+1] = v4.y;
        qreg[i*4+2] = v4.z; qreg[i*4+3] = v4.w;
    }

    float m = -1e30f, l = 0.f;
    float oacc[8] = {};

    for (int k0 = 0; k0 < N; k0 += 64) {
        __syncthreads();            // protect Ks/Vs/Ps from previous iter readers
        #pragma unroll
        for (int i = 0; i < 2; ++i) {
            *(float4*)&Ks[r][c4*8 + i*4] =
                *(const float4*)&Kb[(size_t)(k0 + r) * D + c4*8 + i*4];
            *(float4*)&Vs[r][c4*8 + i*4] =
                *(const float4*)&Vb[(size_t)(k0 + r) * D + c4*8 + i*4];
        }
        __syncthreads();

        // ---- S phase: 16 keys j = c4*16 .. c4*16+15
        float s[16];
        float mt = -1e30f;
        #pragma unroll
        for (int jj = 0; jj < 16; ++jj) {
            int j = c4 * 16 + jj;
            float acc = 0.f;
            #pragma unroll
            for (int i = 0; i < 32; i += 4) {
                float4 kv = *(const float4*)&Ks[j][i];
                acc += qreg[i]   * kv.x + qreg[i+1] * kv.y
                     + qreg[i+2] * kv.z + qreg[i+3] * kv.w;
            }
            s[jj] = acc * SCALE;
            mt = fmaxf(mt, s[jj]);
        }
        // row max across the 4 lanes of this row
        mt = fmaxf(mt, __shfl_xor(mt, 1));
        mt = fmaxf(mt, __shfl_xor(mt, 2));
        float mnew  = fmaxf(m, mt);
        float alpha = __expf(m - mnew);
        float psum = 0.f;
        #pragma unroll
        for (int jj = 0; jj < 16; ++jj) {
            s[jj] = __expf(s[jj] - mnew);
            psum += s[jj];
        }
        psum += __shfl_xor(psum, 1);
        psum += __shfl_xor(psum, 2);
        l = l * alpha + psum;
        m = mnew;
        #pragma unroll
        for (int i = 0; i < 8; ++i) oacc[i] *= alpha;

        // publish P (vectorized)
        #pragma unroll
        for (int q4 = 0; q4 < 4; ++q4)
            *(float4*)&Ps[r][c4*16 + q4*4] =
                make_float4(s[q4*4+0], s[q4*4+1], s[q4*4+2], s[q4*4+3]);
        __syncthreads();

        // ---- PV phase: row r, dims d = c4*8 .. +8
        #pragma unroll
        for (int j4 = 0; j4 < 16; ++j4) {
            float4 p4 = *(const float4*)&Ps[r][j4*4];
            float pv[4] = {p4.x, p4.y, p4.z, p4.w};
            #pragma unroll
            for (int u = 0; u < 4; ++u) {
                int j = j4*4 + u;
                float4 v0 = *(const float4*)&Vs[j][c4*8];
                float4 v1 = *(const float4*)&Vs[j][c4*8+4];
                oacc[0] += pv[u]*v0.x; oacc[1] += pv[u]*v0.y;
                oacc[2] += pv[u]*v0.z; oacc[3] += pv[u]*v0.w;
                oacc[4] += pv[u]*v1.x; oacc[5] += pv[u]*v1.y;
                oacc[6] += pv[u]*v1.z; oacc[7] += pv[u]*v1.w;
            }
        }
    }

    // epilogue: normalize, store O[b][h*32 + c4*8 + i][n0 + r]
    float inv = 1.f / l;
    size_t base = (((size_t)b * CH) + h * HD + c4 * 8) * (size_t)N + (n0 + r);
    #pragma unroll
    for (int i = 0; i < 8; ++i)
        O[base + (size_t)i * N] = oacc[i] * inv;
}

// ---------------------------------------------------------------------------
extern "C" void kernel_launch(void* const* d_in, const int* in_sizes, int n_in,
                              void* d_out, int out_size, void* d_ws, size_t ws_size,
                              hipStream_t stream) {
    const float* x  = (const float*)d_in[0];
    const float* Wq = (const float*)d_in[1];
    const float* bq = (const float*)d_in[2];
    const float* Wk = (const float*)d_in[3];
    const float* bk = (const float*)d_in[4];
    const float* Wv = (const float*)d_in[5];
    const float* bv = (const float*)d_in[6];
    const float* Wo = (const float*)d_in[7];
    const float* bo = (const float*)d_in[8];
    float* out = (float*)d_out;

    // workspace: q, k, v ([B*NH][N][32] each) + o_mid ([B][C][N])
    const size_t elems = (size_t)BATCH * CH * NPOS;   // 1,179,648
    float* q  = (float*)d_ws;
    float* k  = q  + elems;
    float* v  = k  + elems;
    float* om = v  + elems;
    (void)ws_size; (void)in_sizes; (void)n_in; (void)out_size;

    dim3 gg(NPOS / 64, CH / 64, BATCH);   // 36 x 4 x 2
    dim3 bb(256);
    hipLaunchKernelGGL(proj_gemm, gg, bb, 0, stream, x, Wq, bq, q, 1);
    hipLaunchKernelGGL(proj_gemm, gg, bb, 0, stream, x, Wk, bk, k, 1);
    hipLaunchKernelGGL(proj_gemm, gg, bb, 0, stream, x, Wv, bv, v, 1);
    hipLaunchKernelGGL(attn_kernel, dim3(NPOS / 64, BATCH * NH), bb, 0, stream,
                       q, k, v, om);
    hipLaunchKernelGGL(proj_gemm, gg, bb, 0, stream, om, Wo, bo, out, 0);
}

// Round 2
// 180.777 us; speedup vs baseline: 4.0185x; 4.0185x over previous
//
#include <hip/hip_runtime.h>
#include <hip/hip_bf16.h>

// Problem constants
#define BATCH 2
#define CH 256
#define NH 8
#define HD 32
#define NPOS 2304            // 48*48
#define SCALE 0.17677669529663687f   // 32^-0.5

typedef __attribute__((ext_vector_type(8))) short short8;   // 8 x bf16 (4 VGPRs)
typedef __attribute__((ext_vector_type(4))) float f32x4;

__device__ __forceinline__ unsigned short f2bf(float f) {
    unsigned int u = __builtin_bit_cast(unsigned int, f);
    u += 0x7FFFu + ((u >> 16) & 1u);     // round-to-nearest-even
    return (unsigned short)(u >> 16);
}

// ---------------------------------------------------------------------------
// Tiled fp32 GEMM: acc[o][n] = sum_c W[o][c] * X[c][n] + bias[o], then *scale.
// X: [B][C][N]. W: [C][C] row-major [o][c].
// layout 0: fp32 Y[((b*C + o)*N + n)]                         (final output)
// layout 1: bf16 Y[((b*NH + o/32)*N + n)*32 + o%32]           (q/k heads)
// layout 2: bf16 Y[((b*NH + o/32)*32 + o%32)*N + n]           (v transposed)
// ---------------------------------------------------------------------------
__global__ __launch_bounds__(256) void proj_gemm(
    const float* __restrict__ X,
    const float* __restrict__ W,
    const float* __restrict__ bias,
    void* __restrict__ Yv,
    int layout, float scale)
{
    const int N = NPOS, C = CH;
    int b  = blockIdx.z;
    int n0 = blockIdx.x * 64;
    int o0 = blockIdx.y * 64;
    const float* Xb = X + (size_t)b * C * N;

    __shared__ float Xs[16][64];
    __shared__ float Ws[16][65];

    int t  = threadIdx.x;
    int oo = (t & 15) * 4;
    int nn = (t >> 4) * 4;

    float acc[4][4] = {};

    for (int c0 = 0; c0 < C; c0 += 16) {
        {
            int kc = t >> 6;
            int nl = t & 63;
            #pragma unroll
            for (int i = 0; i < 4; ++i)
                Xs[kc + i * 4][nl] = Xb[(size_t)(c0 + kc + i * 4) * N + n0 + nl];
        }
        {
            int ol = t >> 4;
            int kc = t & 15;
            #pragma unroll
            for (int i = 0; i < 4; ++i)
                Ws[kc][ol + i * 16] = W[(size_t)(o0 + ol + i * 16) * C + c0 + kc];
        }
        __syncthreads();
        #pragma unroll
        for (int kc = 0; kc < 16; ++kc) {
            float xr[4], wr[4];
            #pragma unroll
            for (int i = 0; i < 4; ++i) xr[i] = Xs[kc][nn + i];
            #pragma unroll
            for (int i = 0; i < 4; ++i) wr[i] = Ws[kc][oo + i];
            #pragma unroll
            for (int i = 0; i < 4; ++i)
                #pragma unroll
                for (int j = 0; j < 4; ++j)
                    acc[i][j] += wr[i] * xr[j];
        }
        __syncthreads();
    }

    #pragma unroll
    for (int i = 0; i < 4; ++i) {
        int o = o0 + oo + i;
        float bv = bias[o];
        #pragma unroll
        for (int j = 0; j < 4; ++j) {
            int n = n0 + nn + j;
            float v = (acc[i][j] + bv) * scale;
            if (layout == 0) {
                ((float*)Yv)[((size_t)b * C + o) * N + n] = v;
            } else if (layout == 1) {
                ((unsigned short*)Yv)[(((size_t)b * NH + (o >> 5)) * N + n) * HD + (o & 31)] = f2bf(v);
            } else {
                ((unsigned short*)Yv)[(((size_t)b * NH + (o >> 5)) * HD + (o & 31)) * N + n] = f2bf(v);
            }
        }
    }
}

// ---------------------------------------------------------------------------
// Flash attention, bf16 MFMA (16x16x32). Q,K: [bh][N][32] bf16 (Q pre-scaled).
// V: [bh][32][N] bf16 (transposed). Om: fp32 [B][C][N].
// Block = 256 threads = 4 waves; each wave owns 16 Q-rows, fully independent
// (per-wave private LDS for P; NO __syncthreads in the loop).
// ---------------------------------------------------------------------------
__global__ __launch_bounds__(256) void attn_mfma(
    const unsigned short* __restrict__ Q,
    const unsigned short* __restrict__ K,
    const unsigned short* __restrict__ V,
    float* __restrict__ Om)
{
    const int N = NPOS;
    int bh = blockIdx.y;            // 0..15
    int b = bh >> 3, h = bh & 7;
    int n0 = blockIdx.x * 64;
    int t = threadIdx.x;
    int w = t >> 6, lane = t & 63;
    int lo = lane & 15, hi = lane >> 4;

    // per-wave private P tile: 16 rows x 64 keys bf16, XOR-swizzled 16B blocks
    __shared__ unsigned short Pl[4][1024];

    // A-frag: Q[n0 + w*16 + lo][hi*8 .. +7] (16B contiguous)
    short8 qa = *(const short8*)(Q + ((size_t)bh * N + n0 + w * 16 + lo) * HD + hi * 8);

    const unsigned short* Kb = K + (size_t)bh * N * HD;
    const unsigned short* Vb = V + (size_t)bh * HD * N;

    f32x4 oacc[2] = {{0.f,0.f,0.f,0.f},{0.f,0.f,0.f,0.f}};
    float m[4], l[4];
    #pragma unroll
    for (int r = 0; r < 4; ++r) { m[r] = -1e30f; l[r] = 0.f; }

    for (int k0 = 0; k0 < N; k0 += 64) {
        // ---- S = (Q*SCALE) K^T : 4 MFMAs (16 keys each)
        f32x4 s[4];
        #pragma unroll
        for (int g = 0; g < 4; ++g) {
            short8 kf = *(const short8*)(Kb + (size_t)(k0 + g * 16 + lo) * HD + hi * 8);
            s[g] = __builtin_amdgcn_mfma_f32_16x16x32_bf16(qa, kf, (f32x4){0.f,0.f,0.f,0.f}, 0, 0, 0);
        }
        // ---- online softmax; lane holds rows (hi*4+r), key col g*16+lo
        float mnew[4], alpha[4];
        #pragma unroll
        for (int r = 0; r < 4; ++r) {
            float mx = fmaxf(fmaxf(s[0][r], s[1][r]), fmaxf(s[2][r], s[3][r]));
            mx = fmaxf(mx, __shfl_xor(mx, 1));
            mx = fmaxf(mx, __shfl_xor(mx, 2));
            mx = fmaxf(mx, __shfl_xor(mx, 4));
            mx = fmaxf(mx, __shfl_xor(mx, 8));
            mnew[r] = fmaxf(m[r], mx);
            alpha[r] = __expf(m[r] - mnew[r]);
            m[r] = mnew[r];
        }
        #pragma unroll
        for (int g = 0; g < 4; ++g)
            #pragma unroll
            for (int r = 0; r < 4; ++r)
                s[g][r] = __expf(s[g][r] - mnew[r]);
        #pragma unroll
        for (int r = 0; r < 4; ++r) {
            float ps = (s[0][r] + s[1][r]) + (s[2][r] + s[3][r]);
            ps += __shfl_xor(ps, 1);
            ps += __shfl_xor(ps, 2);
            ps += __shfl_xor(ps, 4);
            ps += __shfl_xor(ps, 8);
            l[r] = l[r] * alpha[r] + ps;
        }
        #pragma unroll
        for (int df = 0; df < 2; ++df)
            #pragma unroll
            for (int r = 0; r < 4; ++r)
                oacc[df][r] *= alpha[r];

        // ---- P -> LDS bf16, swizzle: 16B-block index ^= (row&7)
        #pragma unroll
        for (int g = 0; g < 4; ++g) {
            int blk = g * 2 + (lo >> 3);
            #pragma unroll
            for (int r = 0; r < 4; ++r) {
                int row = hi * 4 + r;
                Pl[w][row * 64 + ((blk ^ (row & 7)) * 8) + (lo & 7)] = f2bf(s[g][r]);
            }
        }

        // ---- O += P V : A-frag from swizzled LDS, B-frag from V^T rows
        #pragma unroll
        for (int c = 0; c < 2; ++c) {
            short8 pa = *(const short8*)&Pl[w][lo * 64 + (((c * 4 + hi) ^ (lo & 7)) * 8)];
            #pragma unroll
            for (int df = 0; df < 2; ++df) {
                short8 vf = *(const short8*)(Vb + (size_t)(df * 16 + lo) * N + k0 + c * 32 + hi * 8);
                oacc[df] = __builtin_amdgcn_mfma_f32_16x16x32_bf16(pa, vf, oacc[df], 0, 0, 0);
            }
        }
    }

    // ---- epilogue: normalize, store fp32 Om[b][h*32 + df*16 + lo][n]
    #pragma unroll
    for (int r = 0; r < 4; ++r) l[r] = 1.f / l[r];
    int nrow = n0 + w * 16 + hi * 4;
    #pragma unroll
    for (int df = 0; df < 2; ++df) {
        f32x4 ov;
        #pragma unroll
        for (int r = 0; r < 4; ++r) ov[r] = oacc[df][r] * l[r];
        *(f32x4*)&Om[((size_t)b * CH + h * HD + df * 16 + lo) * N + nrow] = ov;
    }
}

// ---------------------------------------------------------------------------
extern "C" void kernel_launch(void* const* d_in, const int* in_sizes, int n_in,
                              void* d_out, int out_size, void* d_ws, size_t ws_size,
                              hipStream_t stream) {
    const float* x  = (const float*)d_in[0];
    const float* Wq = (const float*)d_in[1];
    const float* bq = (const float*)d_in[2];
    const float* Wk = (const float*)d_in[3];
    const float* bk = (const float*)d_in[4];
    const float* Wv = (const float*)d_in[5];
    const float* bv = (const float*)d_in[6];
    const float* Wo = (const float*)d_in[7];
    const float* bo = (const float*)d_in[8];
    float* out = (float*)d_out;

    const size_t E = (size_t)BATCH * CH * NPOS;   // 1,179,648
    unsigned short* qb = (unsigned short*)d_ws;   // [bh][N][32] bf16 (pre-scaled)
    unsigned short* kb = qb + E;                  // [bh][N][32] bf16
    unsigned short* vT = kb + E;                  // [bh][32][N] bf16
    float*          om = (float*)(vT + E);        // [B][C][N] fp32
    (void)ws_size; (void)in_sizes; (void)n_in; (void)out_size;

    dim3 gg(NPOS / 64, CH / 64, BATCH);   // 36 x 4 x 2
    dim3 bb(256);
    hipLaunchKernelGGL(proj_gemm, gg, bb, 0, stream, x, Wq, bq, (void*)qb, 1, SCALE);
    hipLaunchKernelGGL(proj_gemm, gg, bb, 0, stream, x, Wk, bk, (void*)kb, 1, 1.0f);
    hipLaunchKernelGGL(proj_gemm, gg, bb, 0, stream, x, Wv, bv, (void*)vT, 2, 1.0f);
    hipLaunchKernelGGL(attn_mfma, dim3(NPOS / 64, BATCH * NH), bb, 0, stream,
                       qb, kb, vT, om);
    hipLaunchKernelGGL(proj_gemm, gg, bb, 0, stream, om, Wo, bo, (void*)out, 0, 1.0f);
}

// Round 3
// 139.701 us; speedup vs baseline: 5.2000x; 1.2940x over previous
//
#include <hip/hip_runtime.h>
#include <hip/hip_bf16.h>

// Problem constants
#define BATCH 2
#define CH 256
#define NH 8
#define HD 32
#define NPOS 2304            // 48*48
#define SCALE 0.17677669529663687f   // 32^-0.5

typedef __attribute__((ext_vector_type(8))) short short8;   // 8 x bf16 (4 VGPRs)
typedef __attribute__((ext_vector_type(4))) short short4e;  // 4 x bf16 (8B)
typedef __attribute__((ext_vector_type(4))) float f32x4;

__device__ __forceinline__ unsigned short f2bf(float f) {
    unsigned int u = __builtin_bit_cast(unsigned int, f);
    u += 0x7FFFu + ((u >> 16) & 1u);     // round-to-nearest-even
    return (unsigned short)(u >> 16);
}

// ---------------------------------------------------------------------------
// Convert 4 fp32 [256x256] weight matrices to bf16 (concatenated dst).
// grid (64, 4), block 256: thread handles 4 elements.
// ---------------------------------------------------------------------------
__global__ __launch_bounds__(256) void convert_w(
    const float* __restrict__ Wq, const float* __restrict__ Wk,
    const float* __restrict__ Wv, const float* __restrict__ Wo,
    unsigned short* __restrict__ dst)
{
    int which = blockIdx.y;
    const float* src = (which == 0) ? Wq : (which == 1) ? Wk : (which == 2) ? Wv : Wo;
    unsigned short* d = dst + (size_t)which * CH * CH;
    int i = (blockIdx.x * 256 + threadIdx.x) * 4;
    f32x4 v = *(const f32x4*)&src[i];
    short4e o;
    #pragma unroll
    for (int j = 0; j < 4; ++j) o[j] = (short)f2bf(v[j]);
    *(short4e*)&d[i] = o;
}

// ---------------------------------------------------------------------------
// Transpose+convert: x fp32 [B][C][N] -> xT bf16 [B][N][C].
// grid (N/32, C/32, B), block 256. 32x32 tiles via LDS.
// ---------------------------------------------------------------------------
__global__ __launch_bounds__(256) void transpose_x(
    const float* __restrict__ x, unsigned short* __restrict__ xT)
{
    int b = blockIdx.z, c0 = blockIdx.y * 32, n0 = blockIdx.x * 32;
    __shared__ float Ts[32][33];
    int t = threadIdx.x;
    int col = t & 31, row = t >> 5;      // row 0..7
    #pragma unroll
    for (int i = 0; i < 4; ++i)
        Ts[row + i * 8][col] = x[((size_t)b * CH + c0 + row + i * 8) * NPOS + n0 + col];
    __syncthreads();
    #pragma unroll
    for (int i = 0; i < 4; ++i)
        xT[((size_t)b * NPOS + n0 + row + i * 8) * CH + c0 + col] = f2bf(Ts[col][row + i * 8]);
}

// ---------------------------------------------------------------------------
// Fused QKV GEMM via bf16 MFMA. xT: [B][N][C] bf16. Wb: q|k|v bf16 [o][c].
// Outputs: q,k bf16 [(b*NH+h)*N + n]*32 + d   (q pre-scaled by SCALE)
//          v  bf16 [(b*NH+h)*32 + d]*N + n    (transposed)
// Block 256 = 4 waves; tile 64 o x 64 n; wave owns 16 o-rows x 64 n.
// ---------------------------------------------------------------------------
__global__ __launch_bounds__(256) void qkv_gemm(
    const unsigned short* __restrict__ xT,
    const unsigned short* __restrict__ Wb,
    const float* __restrict__ bq, const float* __restrict__ bk,
    const float* __restrict__ bv,
    unsigned short* __restrict__ qout, unsigned short* __restrict__ kout,
    unsigned short* __restrict__ vout)
{
    int b = blockIdx.z;
    int n0 = blockIdx.x * 64;
    int o0 = blockIdx.y * 64;
    int t = threadIdx.x, w = t >> 6, lane = t & 63;
    int lo = lane & 15, hi = lane >> 4;
    int ob = o0 + w * 16;

    const unsigned short* Wq = Wb;
    const unsigned short* Wk = Wb + (size_t)CH * CH;
    const unsigned short* Wv = Wb + (size_t)2 * CH * CH;
    const unsigned short* xb = xT + ((size_t)b * NPOS + n0) * CH;

    f32x4 aq[4] = {}, ak[4] = {}, av[4] = {};

    for (int k0 = 0; k0 < CH; k0 += 32) {
        short8 wqf = *(const short8*)&Wq[(size_t)(ob + lo) * CH + k0 + hi * 8];
        short8 wkf = *(const short8*)&Wk[(size_t)(ob + lo) * CH + k0 + hi * 8];
        short8 wvf = *(const short8*)&Wv[(size_t)(ob + lo) * CH + k0 + hi * 8];
        #pragma unroll
        for (int g = 0; g < 4; ++g) {
            short8 xf = *(const short8*)&xb[(size_t)(g * 16 + lo) * CH + k0 + hi * 8];
            aq[g] = __builtin_amdgcn_mfma_f32_16x16x32_bf16(wqf, xf, aq[g], 0, 0, 0);
            ak[g] = __builtin_amdgcn_mfma_f32_16x16x32_bf16(wkf, xf, ak[g], 0, 0, 0);
            av[g] = __builtin_amdgcn_mfma_f32_16x16x32_bf16(wvf, xf, av[g], 0, 0, 0);
        }
    }

    int h = ob >> 5;
    int olow = (ob & 31) + hi * 4;
    #pragma unroll
    for (int g = 0; g < 4; ++g) {
        int n = n0 + g * 16 + lo;
        size_t qkbase = ((size_t)(b * NH + h) * NPOS + n) * HD + olow;
        short4e pq, pk;
        #pragma unroll
        for (int r = 0; r < 4; ++r) {
            int o = ob + hi * 4 + r;
            pq[r] = (short)f2bf((aq[g][r] + bq[o]) * SCALE);
            pk[r] = (short)f2bf(ak[g][r] + bk[o]);
        }
        *(short4e*)&qout[qkbase] = pq;
        *(short4e*)&kout[qkbase] = pk;
        size_t vbase = ((size_t)(b * NH + h) * HD + olow) * NPOS + n;
        #pragma unroll
        for (int r = 0; r < 4; ++r)
            vout[vbase + (size_t)r * NPOS] = f2bf(av[g][r] + bv[ob + hi * 4 + r]);
    }
}

// ---------------------------------------------------------------------------
// Flash attention, bf16 MFMA, 128-key tiles. One wave per block (16 Q-rows).
// Q,K: [bh][N][32] bf16 (Q pre-scaled). V: [bh][32][N] bf16.
// Output: omT bf16 [B][N][C] (ready as GEMM B-operand for Wo projection).
// ---------------------------------------------------------------------------
__global__ __launch_bounds__(64) void attn_mfma(
    const unsigned short* __restrict__ Q,
    const unsigned short* __restrict__ K,
    const unsigned short* __restrict__ V,
    unsigned short* __restrict__ omT)
{
    const int N = NPOS;
    int bh = blockIdx.y;            // 0..15
    int b = bh >> 3, h = bh & 7;
    int n0 = blockIdx.x * 16;
    int lane = threadIdx.x & 63;
    int lo = lane & 15, hi = lane >> 4;

    // P tile: 16 rows x 128 keys bf16, XOR-swizzled 16B blocks (blk ^= row&7)
    __shared__ unsigned short Pl[2048];

    short8 qa = *(const short8*)(Q + ((size_t)bh * N + n0 + lo) * HD + hi * 8);

    const unsigned short* Kb = K + (size_t)bh * N * HD;
    const unsigned short* Vb = V + (size_t)bh * HD * N;

    f32x4 oacc[2] = {{0.f,0.f,0.f,0.f},{0.f,0.f,0.f,0.f}};
    float m[4], l[4];
    #pragma unroll
    for (int r = 0; r < 4; ++r) { m[r] = -1e30f; l[r] = 0.f; }

    for (int k0 = 0; k0 < N; k0 += 128) {
        // ---- S = (Q*SCALE) K^T : 8 MFMAs (16 keys each)
        f32x4 s[8];
        #pragma unroll
        for (int g = 0; g < 8; ++g) {
            short8 kf = *(const short8*)(Kb + (size_t)(k0 + g * 16 + lo) * HD + hi * 8);
            s[g] = __builtin_amdgcn_mfma_f32_16x16x32_bf16(qa, kf, (f32x4){0.f,0.f,0.f,0.f}, 0, 0, 0);
        }
        // ---- online softmax; lane holds rows (hi*4+r), key col g*16+lo
        float mnew[4], alpha[4];
        #pragma unroll
        for (int r = 0; r < 4; ++r) {
            float mx = fmaxf(fmaxf(fmaxf(s[0][r], s[1][r]), fmaxf(s[2][r], s[3][r])),
                             fmaxf(fmaxf(s[4][r], s[5][r]), fmaxf(s[6][r], s[7][r])));
            mx = fmaxf(mx, __shfl_xor(mx, 1));
            mx = fmaxf(mx, __shfl_xor(mx, 2));
            mx = fmaxf(mx, __shfl_xor(mx, 4));
            mx = fmaxf(mx, __shfl_xor(mx, 8));
            mnew[r] = fmaxf(m[r], mx);
            alpha[r] = __expf(m[r] - mnew[r]);
            m[r] = mnew[r];
        }
        #pragma unroll
        for (int g = 0; g < 8; ++g)
            #pragma unroll
            for (int r = 0; r < 4; ++r)
                s[g][r] = __expf(s[g][r] - mnew[r]);
        #pragma unroll
        for (int r = 0; r < 4; ++r) {
            float ps = ((s[0][r] + s[1][r]) + (s[2][r] + s[3][r]))
                     + ((s[4][r] + s[5][r]) + (s[6][r] + s[7][r]));
            ps += __shfl_xor(ps, 1);
            ps += __shfl_xor(ps, 2);
            ps += __shfl_xor(ps, 4);
            ps += __shfl_xor(ps, 8);
            l[r] = l[r] * alpha[r] + ps;
        }
        #pragma unroll
        for (int df = 0; df < 2; ++df)
            #pragma unroll
            for (int r = 0; r < 4; ++r)
                oacc[df][r] *= alpha[r];

        // ---- P -> LDS bf16, swizzle: 16B-block index ^= (row&7)
        #pragma unroll
        for (int g = 0; g < 8; ++g) {
            int blk = g * 2 + (lo >> 3);
            #pragma unroll
            for (int r = 0; r < 4; ++r) {
                int row = hi * 4 + r;
                Pl[row * 128 + ((blk ^ (row & 7)) * 8) + (lo & 7)] = f2bf(s[g][r]);
            }
        }

        // ---- O += P V : A-frag from swizzled LDS, B-frag from V^T rows
        #pragma unroll
        for (int c = 0; c < 4; ++c) {
            short8 pa = *(const short8*)&Pl[lo * 128 + (((c * 4 + hi) ^ (lo & 7)) * 8)];
            #pragma unroll
            for (int df = 0; df < 2; ++df) {
                short8 vf = *(const short8*)(Vb + (size_t)(df * 16 + lo) * N + k0 + c * 32 + hi * 8);
                oacc[df] = __builtin_amdgcn_mfma_f32_16x16x32_bf16(pa, vf, oacc[df], 0, 0, 0);
            }
        }
    }

    // ---- epilogue: normalize, store bf16 omT[b][n][h*32 + df*16 + lo]
    #pragma unroll
    for (int r = 0; r < 4; ++r) l[r] = 1.f / l[r];
    int nrow = n0 + hi * 4;
    #pragma unroll
    for (int df = 0; df < 2; ++df)
        #pragma unroll
        for (int r = 0; r < 4; ++r)
            omT[((size_t)b * N + nrow + r) * CH + h * HD + df * 16 + lo] =
                f2bf(oacc[df][r] * l[r]);
}

// ---------------------------------------------------------------------------
// Wo GEMM via bf16 MFMA: out fp32 [B][C][N] = Wo . omT^T + bo.
// omT: [B][N][C] bf16 (B-operand). Wo bf16 [o][c] (A-operand).
// ---------------------------------------------------------------------------
__global__ __launch_bounds__(256) void wo_gemm(
    const unsigned short* __restrict__ omT,
    const unsigned short* __restrict__ Wo,
    const float* __restrict__ bo,
    float* __restrict__ out)
{
    int b = blockIdx.z;
    int n0 = blockIdx.x * 64;
    int o0 = blockIdx.y * 64;
    int t = threadIdx.x, w = t >> 6, lane = t & 63;
    int lo = lane & 15, hi = lane >> 4;
    int ob = o0 + w * 16;

    const unsigned short* xb = omT + ((size_t)b * NPOS + n0) * CH;

    f32x4 acc[4] = {};
    for (int k0 = 0; k0 < CH; k0 += 32) {
        short8 wf = *(const short8*)&Wo[(size_t)(ob + lo) * CH + k0 + hi * 8];
        #pragma unroll
        for (int g = 0; g < 4; ++g) {
            short8 xf = *(const short8*)&xb[(size_t)(g * 16 + lo) * CH + k0 + hi * 8];
            acc[g] = __builtin_amdgcn_mfma_f32_16x16x32_bf16(wf, xf, acc[g], 0, 0, 0);
        }
    }

    #pragma unroll
    for (int g = 0; g < 4; ++g) {
        int n = n0 + g * 16 + lo;
        #pragma unroll
        for (int r = 0; r < 4; ++r) {
            int o = ob + hi * 4 + r;
            out[((size_t)b * CH + o) * NPOS + n] = acc[g][r] + bo[o];
        }
    }
}

// ---------------------------------------------------------------------------
extern "C" void kernel_launch(void* const* d_in, const int* in_sizes, int n_in,
                              void* d_out, int out_size, void* d_ws, size_t ws_size,
                              hipStream_t stream) {
    const float* x  = (const float*)d_in[0];
    const float* Wq = (const float*)d_in[1];
    const float* bq = (const float*)d_in[2];
    const float* Wk = (const float*)d_in[3];
    const float* bk = (const float*)d_in[4];
    const float* Wv = (const float*)d_in[5];
    const float* bv = (const float*)d_in[6];
    const float* Wo = (const float*)d_in[7];
    const float* bo = (const float*)d_in[8];
    float* out = (float*)d_out;

    const size_t E  = (size_t)BATCH * CH * NPOS;   // 1,179,648
    const size_t WS = (size_t)CH * CH;             // 65,536
    unsigned short* wbf = (unsigned short*)d_ws;   // 4 weight matrices bf16
    unsigned short* xT  = wbf + 4 * WS;            // [B][N][C] bf16
    unsigned short* qb  = xT + E;                  // [bh][N][32] bf16 (pre-scaled)
    unsigned short* kb  = qb + E;                  // [bh][N][32] bf16
    unsigned short* vT  = kb + E;                  // [bh][32][N] bf16
    unsigned short* om  = vT + E;                  // [B][N][C] bf16
    (void)ws_size; (void)in_sizes; (void)n_in; (void)out_size;

    hipLaunchKernelGGL(convert_w, dim3(64, 4), dim3(256), 0, stream,
                       Wq, Wk, Wv, Wo, wbf);
    hipLaunchKernelGGL(transpose_x, dim3(NPOS / 32, CH / 32, BATCH), dim3(256), 0, stream,
                       x, xT);
    hipLaunchKernelGGL(qkv_gemm, dim3(NPOS / 64, CH / 64, BATCH), dim3(256), 0, stream,
                       xT, wbf, bq, bk, bv, qb, kb, vT);
    hipLaunchKernelGGL(attn_mfma, dim3(NPOS / 16, BATCH * NH), dim3(64), 0, stream,
                       qb, kb, vT, om);
    hipLaunchKernelGGL(wo_gemm, dim3(NPOS / 64, CH / 64, BATCH), dim3(256), 0, stream,
                       om, wbf + 3 * WS, bo, out);
}